// Round 19
// baseline (83.301 us; speedup 1.0000x reference)
//
#include <hip/hip_runtime.h>

#define SEQ 2048
#define DD 128
#define HQ 32
#define HKV 8
#define WIN 512

typedef unsigned short u16;
typedef unsigned int u32;
typedef unsigned long long u64;
typedef __attribute__((ext_vector_type(8))) short bf16x8;
typedef __attribute__((ext_vector_type(4))) float f32x4;
typedef __attribute__((ext_vector_type(2))) float f32x2;

#define SBAR() asm volatile("s_barrier" ::: "memory")
#define WAITV0() asm volatile("s_waitcnt vmcnt(0)" ::: "memory")
#define WAITV8() asm volatile("s_waitcnt vmcnt(8)" ::: "memory")
#define WAITLGKM0() asm volatile("s_waitcnt lgkmcnt(0)" ::: "memory")

__device__ __forceinline__ u16 f2bf(float f) {
  u32 u = __builtin_bit_cast(u32, f);
  u += 0x7FFFu + ((u >> 16) & 1u);
  return (u16)(u >> 16);
}

__device__ __forceinline__ void gl16(const void* g, void* l) {
  __builtin_amdgcn_global_load_lds(
      (const __attribute__((address_space(1))) void*)g,
      (__attribute__((address_space(3))) void*)l, 16, 0, 0);
}

__device__ __forceinline__ u32 cvtpk(float lo, float hi) {
  u32 r;
  asm("v_cvt_pk_bf16_f32 %0, %1, %2" : "=v"(r) : "v"(lo), "v"(hi));
  return r;
}

__device__ __forceinline__ f32x2 pk_mul(f32x2 a, f32x2 b) {
  f32x2 d;
  asm("v_pk_mul_f32 %0, %1, %2" : "=v"(d) : "v"(a), "v"(b));
  return d;
}
__device__ __forceinline__ f32x2 pk_fma(f32x2 a, f32x2 b, f32x2 c) {
  f32x2 d;
  asm("v_pk_fma_f32 %0, %1, %2, %3" : "=v"(d) : "v"(a), "v"(b), "v"(c));
  return d;
}
__device__ __forceinline__ f32x2 pk_add(f32x2 a, f32x2 b) {
  f32x2 d;
  asm("v_pk_add_f32 %0, %1, %2" : "=v"(d) : "v"(a), "v"(b));
  return d;
}

// exp2 argument for capped score pair: x*log2e - C_E - (C_T*log2e)*x^3
__device__ __forceinline__ f32x2 score2(f32x2 x, f32x2 vL2E, f32x2 vmCE, f32x2 vmCTL) {
  f32x2 x2 = pk_mul(x, x);
  f32x2 a1 = pk_fma(x, vL2E, vmCE);
  f32x2 b1 = pk_mul(x2, vmCTL);
  return pk_fma(b1, x, a1);
}

// unpack 2 bf16 (packed u32) -> f32x2
__device__ __forceinline__ f32x2 unpk(u32 wv) {
  f32x2 r;
  r[0] = __builtin_bit_cast(float, wv << 16);
  r[1] = __builtin_bit_cast(float, wv & 0xFFFF0000u);
  return r;
}

// GroupRMSNorm + weight + bf16 + repack to [b][h][s][d]  (K only)
__device__ __forceinline__ void norm_body(
    const float* __restrict__ x, const float* __restrict__ w,
    u16* __restrict__ o, int hshift, int blk, int tid) {
  const int lane = tid & 63;
  const int wv = tid >> 6;
  const int sub = lane >> 5;
  const int l5 = lane & 31;
  const int rid = blk * 8 + wv * 2 + sub;   // flattened (b,s,h)
  const int H = 1 << hshift;
  const int hh = rid & (H - 1);
  const int s = (rid >> hshift) & (SEQ - 1);
  const int b = rid >> (hshift + 11);
  const float4 xv = *(reinterpret_cast<const float4*>(x + (size_t)rid * DD) + l5);
  float ssq = xv.x * xv.x + xv.y * xv.y + xv.z * xv.z + xv.w * xv.w;
  ssq += __shfl_xor(ssq, 1);
  ssq += __shfl_xor(ssq, 2);
  ssq += __shfl_xor(ssq, 4);
  ssq += __shfl_xor(ssq, 8);
  ssq += __shfl_xor(ssq, 16);
  const float inv = rsqrtf(ssq * (1.0f / 128.0f) + 1e-5f);
  const float4 wv4 = *(reinterpret_cast<const float4*>(w + hh * DD) + l5);
  const u16 o0 = f2bf(xv.x * inv * wv4.x);
  const u16 o1 = f2bf(xv.y * inv * wv4.y);
  const u16 o2 = f2bf(xv.z * inv * wv4.z);
  const u16 o3 = f2bf(xv.w * inv * wv4.w);
  const size_t oo = (((size_t)b * H + hh) * SEQ + s) * DD + l5 * 4;
  uint2 pk;
  pk.x = (u32)o0 | ((u32)o1 << 16);
  pk.y = (u32)o2 | ((u32)o3 << 16);
  *reinterpret_cast<uint2*>(o + oo) = pk;
}

// V: fp32 [b][s][h][d] -> bf16 transposed [b][h][d][s]
__device__ __forceinline__ void transv_body(
    const float* __restrict__ v, u16* __restrict__ vt, int bid, int t) {
  const int st = bid & 31;
  const int h = (bid >> 5) & 7;
  const int b = bid >> 8;
  const int sbase = st * 64;
  const int d = t & 127;
  const int sch = (t >> 7) * 32;
  const size_t oo = (((size_t)(b * HKV + h)) * DD + d) * SEQ + sbase + sch;
#pragma unroll
  for (int q8 = 0; q8 < 4; ++q8) {
    uint4 o;
    u32 c[4];
#pragma unroll
    for (int p = 0; p < 4; ++p) {
      const int ss0 = q8 * 8 + p * 2;
      const int s0 = sbase + sch + ss0;
      const float a0 = v[((size_t)(b * SEQ + s0) * HKV + h) * DD + d];
      const float a1 = v[((size_t)(b * SEQ + s0 + 1) * HKV + h) * DD + d];
      c[p] = (u32)f2bf(a0) | ((u32)f2bf(a1) << 16);
    }
    o.x = c[0]; o.y = c[1]; o.z = c[2]; o.w = c[3];
    *reinterpret_cast<uint4*>(vt + oo + q8 * 8) = o;
  }
}

__global__ void __launch_bounds__(256) prep_kernel(
    const float* __restrict__ k, const float* __restrict__ v,
    const float* __restrict__ kw, u16* __restrict__ kn, u16* __restrict__ vt) {
  const int blk = blockIdx.x;
  const int tid = threadIdx.x;
  if (blk < 4096) {
    norm_body(k, kw, kn, 3, blk, tid);
  } else {
    transv_body(v, vt, blk - 4096, tid);
  }
}

__global__ void __launch_bounds__(256, 2) attn_kernel(
    const float* __restrict__ q32, const float* __restrict__ qw,
    const u16* __restrict__ kn, const u16* __restrict__ vt,
    float* __restrict__ out) {
  __shared__ char smem[65552];   // 4 x 16KB K buffers + 16B mask
  const int tid = threadIdx.x;
  const int w = tid >> 6;
  const int lane = tid & 63;
  const int c = lane & 15;
  const int g = lane >> 4;

  // 2048 blocks; XCD-locality remap; qt reversed so heavy blocks go first.
  const int p = blockIdx.x;
  const int bid = ((p & 7) << 8) + (p >> 3);
  const int qt = (bid & 127) ^ 127;
  const int hk = (bid >> 7) & 7;
  const int b = bid >> 10;
  const int i0 = qt * 16;
  const int h = hk * 4 + w;

  const u16* kbp = kn + (size_t)(b * HKV + hk) * SEQ * DD;
  const u16* vbp = vt + (size_t)(b * HKV + hk) * DD * SEQ;

  int ks = i0 - WIN;
  ks = (ks < 0) ? 0 : (ks & ~63);
  const int ntl = (i0 + 16 - ks + 63) >> 6;   // 64-key tiles (<=9)

  // -------- staging (XOR-swizzled global source, linear LDS dest) ----
  auto stageK = [&](int kb, int bufoff) {   // 64 keys x 256B = 16KB
    char* dst = smem + bufoff;
#pragma unroll
    for (int ci = 0; ci < 4; ++ci) {
      const int call = w * 4 + ci;
      const int row = call * 4 + g;
      const int ch = c ^ (row & 7);
      gl16(kbp + (size_t)(kb + row) * DD + ch * 8, dst + call * 1024);
    }
  };
  auto stageV = [&](int kb, int bufoff) {   // [128 dims][128B=64 keys] = 16KB
    char* dst = smem + bufoff;
#pragma unroll
    for (int ci = 0; ci < 4; ++ci) {
      const int call = w * 4 + ci;
      const int vrow = call * 8 + (lane >> 3);
      const int vch = (lane & 7) ^ (vrow & 7);
      gl16(vbp + (size_t)vrow * SEQ + kb + vch * 8, dst + call * 1024);
    }
  };

  // ---- Q (non-temporal) loads; weights loaded after reduce ----
  const float* qf = q32 + (((size_t)b * SEQ + i0 + c) * HQ + h) * DD;
  const float* wf = qw + h * DD;
  f32x4 qx[4][2];
#pragma unroll
  for (int kt = 0; kt < 4; ++kt) {
    qx[kt][0] = __builtin_nontemporal_load(
        reinterpret_cast<const f32x4*>(qf + kt * 32 + g * 8));
    qx[kt][1] = __builtin_nontemporal_load(
        reinterpret_cast<const f32x4*>(qf + kt * 32 + g * 8 + 4));
  }

  // prologue: stage pairs 0 and 1 (tiles 0..3); norm math hides under flight
  stageK(ks, 0);
  if (ntl > 1) stageK(ks + 64, 16384);
  if (ntl > 2) stageK(ks + 128, 32768);
  if (ntl > 3) stageK(ks + 192, 49152);

  // ---- fused Q GroupRMSNorm -> bf16 fragments ----
  union AQ { bf16x8 v; u32 w4[4]; };
  AQ aq[4];
  {
    float ss = 0.0f;
#pragma unroll
    for (int kt = 0; kt < 4; ++kt) {
#pragma unroll
      for (int half = 0; half < 2; ++half) {
        const f32x4 a = qx[kt][half];
        ss = fmaf(a[0], a[0], ss); ss = fmaf(a[1], a[1], ss);
        ss = fmaf(a[2], a[2], ss); ss = fmaf(a[3], a[3], ss);
      }
    }
    ss += __shfl_xor(ss, 16);
    ss += __shfl_xor(ss, 32);
    const float inv = rsqrtf(ss * (1.0f / 128.0f) + 1e-5f) * 0.08838834764831845f;
#pragma unroll
    for (int kt = 0; kt < 4; ++kt) {
      const f32x4 w0 = *reinterpret_cast<const f32x4*>(wf + kt * 32 + g * 8);
      const f32x4 w1 = *reinterpret_cast<const f32x4*>(wf + kt * 32 + g * 8 + 4);
      const f32x4 a0 = qx[kt][0];
      const f32x4 a1 = qx[kt][1];
      aq[kt].w4[0] = cvtpk(a0[0] * inv * w0[0], a0[1] * inv * w0[1]);
      aq[kt].w4[1] = cvtpk(a0[2] * inv * w0[2], a0[3] * inv * w0[3]);
      aq[kt].w4[2] = cvtpk(a1[0] * inv * w1[0], a1[1] * inv * w1[1]);
      aq[kt].w4[3] = cvtpk(a1[2] * inv * w1[2], a1[3] * inv * w1[3]);
    }
  }

  const f32x2 vL2E = {1.44269504088896f, 1.44269504088896f};
  const f32x2 vmCE = {-43.2808512266689f, -43.2808512266689f};   // -CAP*log2e
  const f32x2 vmCTL = {-5.343315e-4f, -5.343315e-4f};            // -log2e/(3*CAP^2)

  u32 ebuf[9][8];          // unnormalized exp, packed bf16; [tile][nt*2+pair]
  f32x2 lsum2 = {0.0f, 0.0f};

  // one 64-key tile: QK^T + cap + exp -> ebuf[t]
  auto doTile = [&](int t, int bufoff) {
    const int kb = ks + t * 64;
    const char* kbuf = smem + bufoff;
    f32x4 sc[4] = {};
    __builtin_amdgcn_s_setprio(1);
#pragma unroll
    for (int nt = 0; nt < 4; ++nt) {
      const int jb = kb + nt * 16;
      if (jb > i0 + 15 || jb + 15 < i0 - WIN) continue;  // wave-uniform skip
      const int row = nt * 16 + c;
      const int sw = row & 7;
      const char* base = kbuf + row * 256;
#pragma unroll
      for (int kt = 0; kt < 4; ++kt) {
        const bf16x8 bk = *reinterpret_cast<const bf16x8*>(base + (((kt * 4 + g) ^ sw) << 4));
        sc[nt] = __builtin_amdgcn_mfma_f32_16x16x32_bf16(bk, aq[kt].v, sc[nt], 0, 0, 0);
      }
    }
    __builtin_amdgcn_s_setprio(0);

#pragma unroll
    for (int nt = 0; nt < 4; ++nt) {
      const int jb = kb + nt * 16;
      if (jb > i0 + 15 || jb + 15 < i0 - WIN) {
        ebuf[t][nt * 2] = 0;
        ebuf[t][nt * 2 + 1] = 0;
        continue;
      }
      const bool needmask = (jb + 15 > i0) || (jb < i0 + 15 - WIN);
      f32x2 lo = __builtin_shufflevector(sc[nt], sc[nt], 0, 1);
      f32x2 hi = __builtin_shufflevector(sc[nt], sc[nt], 2, 3);
      const f32x2 a0 = score2(lo, vL2E, vmCE, vmCTL);
      const f32x2 a1 = score2(hi, vL2E, vmCE, vmCTL);
      float e0 = __builtin_amdgcn_exp2f(a0[0]);
      float e1 = __builtin_amdgcn_exp2f(a0[1]);
      float e2 = __builtin_amdgcn_exp2f(a1[0]);
      float e3 = __builtin_amdgcn_exp2f(a1[1]);
      if (needmask) {
        const int difg = i0 + c - jb - g * 4;   // i - j for r=0
        e0 = ((u32)(difg - 0) <= WIN) ? e0 : 0.0f;
        e1 = ((u32)(difg - 1) <= WIN) ? e1 : 0.0f;
        e2 = ((u32)(difg - 2) <= WIN) ? e2 : 0.0f;
        e3 = ((u32)(difg - 3) <= WIN) ? e3 : 0.0f;
      }
      ebuf[t][nt * 2] = cvtpk(e0, e1);
      ebuf[t][nt * 2 + 1] = cvtpk(e2, e3);
      const f32x2 eA = {e0, e1};
      const f32x2 eB = {e2, e3};
      lsum2 = pk_add(lsum2, pk_add(eA, eB));
    }
  };

  // ---- pass 1: 2 tiles per round, 4 buffers (pairs A/B), 5 rounds ----
#pragma unroll
  for (int pt = 0; pt < 5; ++pt) {
    const int t0 = pt * 2;
    if (t0 >= ntl) continue;                 // block-uniform
    if (pt == 0) {
      if (ntl > 2) { WAITV8(); } else { WAITV0(); }
    } else {
      WAITV0();
    }
    SBAR();
    // stage pair pt+1 into the pair-buffer freed by round pt-1
    if (pt >= 1) {
      const int tn = (pt + 1) * 2;
      const int pb = ((pt + 1) & 1) * 2;
      if (tn < ntl) stageK(ks + tn * 64, pb << 14);
      if (tn + 1 < ntl) stageK(ks + (tn + 1) * 64, (pb + 1) << 14);
    }
    const int pb0 = (pt & 1) * 2;
    doTile(t0, pb0 << 14);
    if (t0 + 1 < ntl) doTile(t0 + 1, (pb0 + 1) << 14);
  }

  // ---- reduction + survivor-tile mask (skipping all-zero-clip work is bit-exact) ----
  float l = lsum2[0] + lsum2[1];
  l += __shfl_xor(l, 16);
  l += __shfl_xor(l, 32);
  const float ar = 1.06f / l;
  const float thr = 0.0283018868f * l;       // e > thr  <=>  1.06*e/l - 0.03 > 0

  u32 m9w = 0;
#pragma unroll
  for (int t = 0; t < 9; ++t) {
    if (t >= ntl) continue;
    bool nz = false;
#pragma unroll
    for (int u = 0; u < 8; ++u) {
      const f32x2 ef = unpk(ebuf[t][u]);
      nz = nz || (ef[0] > thr) || (ef[1] > thr);
    }
    if (__any(nz)) m9w |= 1u << t;
  }

  u32* mk = reinterpret_cast<u32*>(smem + 65536);
  mk[w] = m9w;
  WAITLGKM0();
  SBAR();                                    // mask visible + pass-1 K reads done
  const u32 m9 = mk[0] | mk[1] | mk[2] | mk[3];

  // next-survivor nibble table: nibble t = first survivor >= t (15 = none)
  u64 nxtp = 0xFULL << 36;
  {
    int nx = 15;
#pragma unroll
    for (int t = 8; t >= 0; --t) {
      if (m9 & (1u << t)) nx = t;
      nxtp |= (u64)nx << (4 * t);
    }
  }
  const int f0 = (int)(nxtp & 15);
  if (f0 < 9) stageV(ks + f0 * 64, 0);

  const f32x2 var2 = {ar, ar};
  const f32x2 vm003 = {-0.03f, -0.03f};

  f32x4 acc[8] = {};
  int vi = 0;

  // ---- pass 2: survivor tiles only; V double-buffered; chunk skip kept ----
#pragma unroll
  for (int t = 0; t < 9; ++t) {
    if (t >= ntl) continue;
    if (!(m9 & (1u << t))) continue;         // block-uniform (shared mask)
    const int kb = ks + t * 64;
    WAITV0();
    SBAR();
    const int nx2 = (int)((nxtp >> (4 * (t + 1))) & 15);
    if (nx2 < 9) stageV(ks + nx2 * 64, ((vi + 1) & 1) << 14);
    const char* ldsV = smem + ((vi & 1) << 14);

#pragma unroll
    for (int k2 = 0; k2 < 2; ++k2) {
      const int jb2 = kb + k2 * 32;
      if (jb2 > i0 + 15 || jb2 + 31 < i0 - WIN) continue;  // dead 32-key half

      // clip: p = med3(1.06*e/l - 0.03, 0, 1), packed bf16
      u32 cw[4];
#pragma unroll
      for (int u = 0; u < 4; ++u) {
        const f32x2 ef = unpk(ebuf[t][k2 * 4 + u]);
        const f32x2 pr = pk_fma(ef, var2, vm003);
        cw[u] = cvtpk(__builtin_amdgcn_fmed3f(pr[0], 0.0f, 1.0f),
                      __builtin_amdgcn_fmed3f(pr[1], 0.0f, 1.0f));
      }

      // sparsity skip: most chunks are entirely clipped to zero
      const u32 nz = (cw[0] | cw[1]) | (cw[2] | cw[3]);
      if (!__any(nz != 0)) continue;

      // exchange: build PV A-fragment via permlane swaps (no LDS)
      union PU { bf16x8 v; u32 w4[4]; };
      PU pf;
      {
        u32 x0 = cw[0], y0 = cw[2];
        asm("v_permlane32_swap_b32 %0, %1" : "+v"(x0), "+v"(y0));
        asm("v_permlane16_swap_b32 %0, %1" : "+v"(x0), "+v"(y0));
        u32 x1 = cw[1], y1 = cw[3];
        asm("v_permlane32_swap_b32 %0, %1" : "+v"(x1), "+v"(y1));
        asm("v_permlane16_swap_b32 %0, %1" : "+v"(x1), "+v"(y1));
        pf.w4[0] = x0;
        pf.w4[1] = x1;
        pf.w4[2] = y0;
        pf.w4[3] = y1;
      }

      __builtin_amdgcn_s_setprio(1);
#pragma unroll
      for (int dt = 0; dt < 8; ++dt) {
        const int rv = dt * 16 + c;
        const bf16x8 bv = *reinterpret_cast<const bf16x8*>(
            ldsV + rv * 128 + (((k2 * 4 + g) ^ (rv & 7)) << 4));
        acc[dt] = __builtin_amdgcn_mfma_f32_16x16x32_bf16(pf.v, bv, acc[dt], 0, 0, 0);
      }
      __builtin_amdgcn_s_setprio(0);
    }
    ++vi;
  }

  // epilogue: out[b][i][h][d] fp32 (non-temporal); query = i0+4g+r, dim = 16dt+c
#pragma unroll
  for (int r = 0; r < 4; ++r) {
    const int i = i0 + g * 4 + r;
    float* op = out + (((size_t)b * SEQ + i) * HQ + h) * DD + c;
#pragma unroll
    for (int dt = 0; dt < 8; ++dt)
      __builtin_nontemporal_store(acc[dt][r], op + dt * 16);
  }
}

extern "C" void kernel_launch(void* const* d_in, const int* in_sizes, int n_in,
                              void* d_out, int out_size, void* d_ws, size_t ws_size,
                              hipStream_t stream) {
  const float* q = (const float*)d_in[0];
  const float* k = (const float*)d_in[1];
  const float* v = (const float*)d_in[2];
  const float* qw = (const float*)d_in[3];
  const float* kw = (const float*)d_in[4];
  float* out = (float*)d_out;

  u16* kn = (u16*)d_ws;                                  // [2][8][2048][128] bf16
  u16* vt = kn + (size_t)2 * HKV * SEQ * DD;             // [2][8][128][2048] bf16

  prep_kernel<<<4608, 256, 0, stream>>>(k, v, kw, kn, vt);
  attn_kernel<<<2048, 256, 0, stream>>>(q, qw, kn, vt, out);
}

// Round 20
// 75.184 us; speedup vs baseline: 1.1080x; 1.1080x over previous
//
#include <hip/hip_runtime.h>

#define SEQ 2048
#define DD 128
#define HQ 32
#define HKV 8
#define WIN 512

typedef unsigned short u16;
typedef unsigned int u32;
typedef unsigned long long u64;
typedef __attribute__((ext_vector_type(8))) short bf16x8;
typedef __attribute__((ext_vector_type(4))) float f32x4;
typedef __attribute__((ext_vector_type(2))) float f32x2;

#define SBAR() asm volatile("s_barrier" ::: "memory")
#define WAITV0() asm volatile("s_waitcnt vmcnt(0)" ::: "memory")
#define WAITV4() asm volatile("s_waitcnt vmcnt(4)" ::: "memory")
#define WAITLGKM0() asm volatile("s_waitcnt lgkmcnt(0)" ::: "memory")

__device__ __forceinline__ u16 f2bf(float f) {
  u32 u = __builtin_bit_cast(u32, f);
  u += 0x7FFFu + ((u >> 16) & 1u);
  return (u16)(u >> 16);
}

__device__ __forceinline__ void gl16(const void* g, void* l) {
  __builtin_amdgcn_global_load_lds(
      (const __attribute__((address_space(1))) void*)g,
      (__attribute__((address_space(3))) void*)l, 16, 0, 0);
}

__device__ __forceinline__ u32 cvtpk(float lo, float hi) {
  u32 r;
  asm("v_cvt_pk_bf16_f32 %0, %1, %2" : "=v"(r) : "v"(lo), "v"(hi));
  return r;
}

__device__ __forceinline__ f32x2 pk_mul(f32x2 a, f32x2 b) {
  f32x2 d;
  asm("v_pk_mul_f32 %0, %1, %2" : "=v"(d) : "v"(a), "v"(b));
  return d;
}
__device__ __forceinline__ f32x2 pk_fma(f32x2 a, f32x2 b, f32x2 c) {
  f32x2 d;
  asm("v_pk_fma_f32 %0, %1, %2, %3" : "=v"(d) : "v"(a), "v"(b), "v"(c));
  return d;
}
__device__ __forceinline__ f32x2 pk_add(f32x2 a, f32x2 b) {
  f32x2 d;
  asm("v_pk_add_f32 %0, %1, %2" : "=v"(d) : "v"(a), "v"(b));
  return d;
}

// exp2 argument for capped score pair: x*log2e - C_E - (C_T*log2e)*x^3
__device__ __forceinline__ f32x2 score2(f32x2 x, f32x2 vL2E, f32x2 vmCE, f32x2 vmCTL) {
  f32x2 x2 = pk_mul(x, x);
  f32x2 a1 = pk_fma(x, vL2E, vmCE);
  f32x2 b1 = pk_mul(x2, vmCTL);
  return pk_fma(b1, x, a1);
}

// unpack 2 bf16 (packed u32) -> f32x2
__device__ __forceinline__ f32x2 unpk(u32 wv) {
  f32x2 r;
  r[0] = __builtin_bit_cast(float, wv << 16);
  r[1] = __builtin_bit_cast(float, wv & 0xFFFF0000u);
  return r;
}

// GroupRMSNorm + weight + bf16 + repack to [b][h][s][d]  (K only)
__device__ __forceinline__ void norm_body(
    const float* __restrict__ x, const float* __restrict__ w,
    u16* __restrict__ o, int hshift, int blk, int tid) {
  const int lane = tid & 63;
  const int wv = tid >> 6;
  const int sub = lane >> 5;
  const int l5 = lane & 31;
  const int rid = blk * 8 + wv * 2 + sub;   // flattened (b,s,h)
  const int H = 1 << hshift;
  const int hh = rid & (H - 1);
  const int s = (rid >> hshift) & (SEQ - 1);
  const int b = rid >> (hshift + 11);
  const float4 xv = *(reinterpret_cast<const float4*>(x + (size_t)rid * DD) + l5);
  float ssq = xv.x * xv.x + xv.y * xv.y + xv.z * xv.z + xv.w * xv.w;
  ssq += __shfl_xor(ssq, 1);
  ssq += __shfl_xor(ssq, 2);
  ssq += __shfl_xor(ssq, 4);
  ssq += __shfl_xor(ssq, 8);
  ssq += __shfl_xor(ssq, 16);
  const float inv = rsqrtf(ssq * (1.0f / 128.0f) + 1e-5f);
  const float4 wv4 = *(reinterpret_cast<const float4*>(w + hh * DD) + l5);
  const u16 o0 = f2bf(xv.x * inv * wv4.x);
  const u16 o1 = f2bf(xv.y * inv * wv4.y);
  const u16 o2 = f2bf(xv.z * inv * wv4.z);
  const u16 o3 = f2bf(xv.w * inv * wv4.w);
  const size_t oo = (((size_t)b * H + hh) * SEQ + s) * DD + l5 * 4;
  uint2 pk;
  pk.x = (u32)o0 | ((u32)o1 << 16);
  pk.y = (u32)o2 | ((u32)o3 << 16);
  *reinterpret_cast<uint2*>(o + oo) = pk;
}

// V: fp32 [b][s][h][d] -> bf16 transposed [b][h][d][s]
__device__ __forceinline__ void transv_body(
    const float* __restrict__ v, u16* __restrict__ vt, int bid, int t) {
  const int st = bid & 31;
  const int h = (bid >> 5) & 7;
  const int b = bid >> 8;
  const int sbase = st * 64;
  const int d = t & 127;
  const int sch = (t >> 7) * 32;
  const size_t oo = (((size_t)(b * HKV + h)) * DD + d) * SEQ + sbase + sch;
#pragma unroll
  for (int q8 = 0; q8 < 4; ++q8) {
    uint4 o;
    u32 c[4];
#pragma unroll
    for (int p = 0; p < 4; ++p) {
      const int ss0 = q8 * 8 + p * 2;
      const int s0 = sbase + sch + ss0;
      const float a0 = v[((size_t)(b * SEQ + s0) * HKV + h) * DD + d];
      const float a1 = v[((size_t)(b * SEQ + s0 + 1) * HKV + h) * DD + d];
      c[p] = (u32)f2bf(a0) | ((u32)f2bf(a1) << 16);
    }
    o.x = c[0]; o.y = c[1]; o.z = c[2]; o.w = c[3];
    *reinterpret_cast<uint4*>(vt + oo + q8 * 8) = o;
  }
}

__global__ void __launch_bounds__(256) prep_kernel(
    const float* __restrict__ k, const float* __restrict__ v,
    const float* __restrict__ kw, u16* __restrict__ kn, u16* __restrict__ vt) {
  const int blk = blockIdx.x;
  const int tid = threadIdx.x;
  if (blk < 4096) {
    norm_body(k, kw, kn, 3, blk, tid);
  } else {
    transv_body(v, vt, blk - 4096, tid);
  }
}

__global__ void __launch_bounds__(256, 3) attn_kernel(
    const float* __restrict__ q32, const float* __restrict__ qw,
    const u16* __restrict__ kn, const u16* __restrict__ vt,
    float* __restrict__ out) {
  __shared__ char smem[49168];   // 3 x 16KB buffers + 16B mask
  const int tid = threadIdx.x;
  const int w = tid >> 6;
  const int lane = tid & 63;
  const int c = lane & 15;
  const int g = lane >> 4;

  // 2048 blocks; XCD-locality remap; qt reversed so heavy blocks go first.
  const int p = blockIdx.x;
  const int bid = ((p & 7) << 8) + (p >> 3);
  const int qt = (bid & 127) ^ 127;
  const int hk = (bid >> 7) & 7;
  const int b = bid >> 10;
  const int i0 = qt * 16;
  const int h = hk * 4 + w;

  const u16* kbp = kn + (size_t)(b * HKV + hk) * SEQ * DD;
  const u16* vbp = vt + (size_t)(b * HKV + hk) * DD * SEQ;

  int ks = i0 - WIN;
  ks = (ks < 0) ? 0 : (ks & ~63);
  const int ntl = (i0 + 16 - ks + 63) >> 6;   // 64-key tiles (<=9)

  // -------- staging (XOR-swizzled global source, linear LDS dest) ----
  auto stageK = [&](int kb, int bufoff) {   // 64 keys x 256B = 16KB
    char* dst = smem + bufoff;
#pragma unroll
    for (int ci = 0; ci < 4; ++ci) {
      const int call = w * 4 + ci;
      const int row = call * 4 + g;
      const int ch = c ^ (row & 7);
      gl16(kbp + (size_t)(kb + row) * DD + ch * 8, dst + call * 1024);
    }
  };
  auto stageV = [&](int kb, int bufoff) {   // [128 dims][128B=64 keys] = 16KB
    char* dst = smem + bufoff;
#pragma unroll
    for (int ci = 0; ci < 4; ++ci) {
      const int call = w * 4 + ci;
      const int vrow = call * 8 + (lane >> 3);
      const int vch = (lane & 7) ^ (vrow & 7);
      gl16(vbp + (size_t)vrow * SEQ + kb + vch * 8, dst + call * 1024);
    }
  };

  // ---- Q (non-temporal, no L2 pollution) loads only; weights loaded later
  //      (keeps prologue register peak low -> occupancy) ----
  const float* qf = q32 + (((size_t)b * SEQ + i0 + c) * HQ + h) * DD;
  const float* wf = qw + h * DD;
  f32x4 qx[4][2];
#pragma unroll
  for (int kt = 0; kt < 4; ++kt) {
    qx[kt][0] = __builtin_nontemporal_load(
        reinterpret_cast<const f32x4*>(qf + kt * 32 + g * 8));
    qx[kt][1] = __builtin_nontemporal_load(
        reinterpret_cast<const f32x4*>(qf + kt * 32 + g * 8 + 4));
  }

  // kick off first two K tiles; norm math hides under their flight
  stageK(ks, 0);
  if (ntl > 1) stageK(ks + 64, 16384);

  // ---- fused Q GroupRMSNorm -> bf16 fragments ----
  union AQ { bf16x8 v; u32 w4[4]; };
  AQ aq[4];
  {
    float ss = 0.0f;
#pragma unroll
    for (int kt = 0; kt < 4; ++kt) {
#pragma unroll
      for (int half = 0; half < 2; ++half) {
        const f32x4 a = qx[kt][half];
        ss = fmaf(a[0], a[0], ss); ss = fmaf(a[1], a[1], ss);
        ss = fmaf(a[2], a[2], ss); ss = fmaf(a[3], a[3], ss);
      }
    }
    ss += __shfl_xor(ss, 16);
    ss += __shfl_xor(ss, 32);
    const float inv = rsqrtf(ss * (1.0f / 128.0f) + 1e-5f) * 0.08838834764831845f;
#pragma unroll
    for (int kt = 0; kt < 4; ++kt) {
      const f32x4 w0 = *reinterpret_cast<const f32x4*>(wf + kt * 32 + g * 8);
      const f32x4 w1 = *reinterpret_cast<const f32x4*>(wf + kt * 32 + g * 8 + 4);
      const f32x4 a0 = qx[kt][0];
      const f32x4 a1 = qx[kt][1];
      aq[kt].w4[0] = cvtpk(a0[0] * inv * w0[0], a0[1] * inv * w0[1]);
      aq[kt].w4[1] = cvtpk(a0[2] * inv * w0[2], a0[3] * inv * w0[3]);
      aq[kt].w4[2] = cvtpk(a1[0] * inv * w1[0], a1[1] * inv * w1[1]);
      aq[kt].w4[3] = cvtpk(a1[2] * inv * w1[2], a1[3] * inv * w1[3]);
    }
  }

  const f32x2 vL2E = {1.44269504088896f, 1.44269504088896f};
  const f32x2 vmCE = {-43.2808512266689f, -43.2808512266689f};   // -CAP*log2e
  const f32x2 vmCTL = {-5.343315e-4f, -5.343315e-4f};            // -log2e/(3*CAP^2)

  u32 ebuf[9][8];          // unnormalized exp, packed bf16; [tile][nt*2+pair]
  f32x2 lsum2 = {0.0f, 0.0f};

  // ---- pass 1: 3-buffer K rotation, 2-deep prefetch, counted vmcnt ----
#pragma unroll
  for (int t = 0; t < 9; ++t) {
    if (t >= ntl) continue;                  // block-uniform
    const int kb = ks + t * 64;
    if (t + 1 < ntl) { WAITV4(); } else { WAITV0(); }
    SBAR();
    if (t + 2 < ntl) stageK(kb + 128, ((t + 2) % 3) << 14);

    const char* kbuf = smem + ((t % 3) << 14);
    f32x4 sc[4] = {};
    __builtin_amdgcn_s_setprio(1);
#pragma unroll
    for (int nt = 0; nt < 4; ++nt) {
      const int jb = kb + nt * 16;
      if (jb > i0 + 15 || jb + 15 < i0 - WIN) continue;  // wave-uniform skip
      const int row = nt * 16 + c;
      const int sw = row & 7;
      const char* base = kbuf + row * 256;
#pragma unroll
      for (int kt = 0; kt < 4; ++kt) {
        const bf16x8 bk = *reinterpret_cast<const bf16x8*>(base + (((kt * 4 + g) ^ sw) << 4));
        sc[nt] = __builtin_amdgcn_mfma_f32_16x16x32_bf16(bk, aq[kt].v, sc[nt], 0, 0, 0);
      }
    }
    __builtin_amdgcn_s_setprio(0);

#pragma unroll
    for (int nt = 0; nt < 4; ++nt) {
      const int jb = kb + nt * 16;
      if (jb > i0 + 15 || jb + 15 < i0 - WIN) {
        ebuf[t][nt * 2] = 0;
        ebuf[t][nt * 2 + 1] = 0;
        continue;
      }
      const bool needmask = (jb + 15 > i0) || (jb < i0 + 15 - WIN);
      f32x2 lo = __builtin_shufflevector(sc[nt], sc[nt], 0, 1);
      f32x2 hi = __builtin_shufflevector(sc[nt], sc[nt], 2, 3);
      const f32x2 a0 = score2(lo, vL2E, vmCE, vmCTL);
      const f32x2 a1 = score2(hi, vL2E, vmCE, vmCTL);
      float e0 = __builtin_amdgcn_exp2f(a0[0]);
      float e1 = __builtin_amdgcn_exp2f(a0[1]);
      float e2 = __builtin_amdgcn_exp2f(a1[0]);
      float e3 = __builtin_amdgcn_exp2f(a1[1]);
      if (needmask) {
        const int difg = i0 + c - jb - g * 4;   // i - j for r=0
        e0 = ((u32)(difg - 0) <= WIN) ? e0 : 0.0f;
        e1 = ((u32)(difg - 1) <= WIN) ? e1 : 0.0f;
        e2 = ((u32)(difg - 2) <= WIN) ? e2 : 0.0f;
        e3 = ((u32)(difg - 3) <= WIN) ? e3 : 0.0f;
      }
      ebuf[t][nt * 2] = cvtpk(e0, e1);
      ebuf[t][nt * 2 + 1] = cvtpk(e2, e3);
      const f32x2 eA = {e0, e1};
      const f32x2 eB = {e2, e3};
      lsum2 = pk_add(lsum2, pk_add(eA, eB));
    }
  }

  // ---- reduction + survivor-tile mask (skipping all-zero-clip work is bit-exact) ----
  float l = lsum2[0] + lsum2[1];
  l += __shfl_xor(l, 16);
  l += __shfl_xor(l, 32);
  const float ar = 1.06f / l;
  const float thr = 0.0283018868f * l;       // e > thr  <=>  1.06*e/l - 0.03 > 0

  u32 m9w = 0;
#pragma unroll
  for (int t = 0; t < 9; ++t) {
    if (t >= ntl) continue;
    bool nz = false;
#pragma unroll
    for (int u = 0; u < 8; ++u) {
      const f32x2 ef = unpk(ebuf[t][u]);
      nz = nz || (ef[0] > thr) || (ef[1] > thr);
    }
    if (__any(nz)) m9w |= 1u << t;
  }

  u32* mk = reinterpret_cast<u32*>(smem + 49152);
  mk[w] = m9w;
  WAITLGKM0();
  SBAR();                                    // mask visible + pass-1 K reads done
  const u32 m9 = mk[0] | mk[1] | mk[2] | mk[3];

  // next-survivor nibble table: nibble t = first survivor >= t (15 = none)
  u64 nxtp = 0xFULL << 36;
  {
    int nx = 15;
#pragma unroll
    for (int t = 8; t >= 0; --t) {
      if (m9 & (1u << t)) nx = t;
      nxtp |= (u64)nx << (4 * t);
    }
  }
  const int f0 = (int)(nxtp & 15);
  if (f0 < 9) stageV(ks + f0 * 64, 0);

  const f32x2 var2 = {ar, ar};
  const f32x2 vm003 = {-0.03f, -0.03f};

  f32x4 acc[8] = {};
  int vi = 0;

  // ---- pass 2: survivor tiles only; V double-buffered; chunk skip kept ----
#pragma unroll
  for (int t = 0; t < 9; ++t) {
    if (t >= ntl) continue;
    if (!(m9 & (1u << t))) continue;         // block-uniform (shared mask)
    const int kb = ks + t * 64;
    WAITV0();
    SBAR();
    const int nx2 = (int)((nxtp >> (4 * (t + 1))) & 15);
    if (nx2 < 9) stageV(ks + nx2 * 64, ((vi + 1) & 1) << 14);
    const char* ldsV = smem + ((vi & 1) << 14);

#pragma unroll
    for (int k2 = 0; k2 < 2; ++k2) {
      const int jb2 = kb + k2 * 32;
      if (jb2 > i0 + 15 || jb2 + 31 < i0 - WIN) continue;  // dead 32-key half

      // clip: p = med3(1.06*e/l - 0.03, 0, 1), packed bf16
      u32 cw[4];
#pragma unroll
      for (int u = 0; u < 4; ++u) {
        const f32x2 ef = unpk(ebuf[t][k2 * 4 + u]);
        const f32x2 pr = pk_fma(ef, var2, vm003);
        cw[u] = cvtpk(__builtin_amdgcn_fmed3f(pr[0], 0.0f, 1.0f),
                      __builtin_amdgcn_fmed3f(pr[1], 0.0f, 1.0f));
      }

      // sparsity skip: most chunks are entirely clipped to zero
      const u32 nz = (cw[0] | cw[1]) | (cw[2] | cw[3]);
      if (!__any(nz != 0)) continue;

      // exchange: build PV A-fragment via permlane swaps (no LDS)
      union PU { bf16x8 v; u32 w4[4]; };
      PU pf;
      {
        u32 x0 = cw[0], y0 = cw[2];
        asm("v_permlane32_swap_b32 %0, %1" : "+v"(x0), "+v"(y0));
        asm("v_permlane16_swap_b32 %0, %1" : "+v"(x0), "+v"(y0));
        u32 x1 = cw[1], y1 = cw[3];
        asm("v_permlane32_swap_b32 %0, %1" : "+v"(x1), "+v"(y1));
        asm("v_permlane16_swap_b32 %0, %1" : "+v"(x1), "+v"(y1));
        pf.w4[0] = x0;
        pf.w4[1] = x1;
        pf.w4[2] = y0;
        pf.w4[3] = y1;
      }

      __builtin_amdgcn_s_setprio(1);
#pragma unroll
      for (int dt = 0; dt < 8; ++dt) {
        const int rv = dt * 16 + c;
        const bf16x8 bv = *reinterpret_cast<const bf16x8*>(
            ldsV + rv * 128 + (((k2 * 4 + g) ^ (rv & 7)) << 4));
        acc[dt] = __builtin_amdgcn_mfma_f32_16x16x32_bf16(pf.v, bv, acc[dt], 0, 0, 0);
      }
      __builtin_amdgcn_s_setprio(0);
    }
    ++vi;
  }

  // epilogue: out[b][i][h][d] fp32 (non-temporal); query = i0+4g+r, dim = 16dt+c
#pragma unroll
  for (int r = 0; r < 4; ++r) {
    const int i = i0 + g * 4 + r;
    float* op = out + (((size_t)b * SEQ + i) * HQ + h) * DD + c;
#pragma unroll
    for (int dt = 0; dt < 8; ++dt)
      __builtin_nontemporal_store(acc[dt][r], op + dt * 16);
  }
}

extern "C" void kernel_launch(void* const* d_in, const int* in_sizes, int n_in,
                              void* d_out, int out_size, void* d_ws, size_t ws_size,
                              hipStream_t stream) {
  const float* q = (const float*)d_in[0];
  const float* k = (const float*)d_in[1];
  const float* v = (const float*)d_in[2];
  const float* qw = (const float*)d_in[3];
  const float* kw = (const float*)d_in[4];
  float* out = (float*)d_out;

  u16* kn = (u16*)d_ws;                                  // [2][8][2048][128] bf16
  u16* vt = kn + (size_t)2 * HKV * SEQ * DD;             // [2][8][128][2048] bf16

  prep_kernel<<<4608, 256, 0, stream>>>(k, v, kw, kn, vt);
  attn_kernel<<<2048, 256, 0, stream>>>(q, qw, kn, vt, out);
}